// Round 1
// baseline (345.449 us; speedup 1.0000x reference)
//
#include <hip/hip_runtime.h>

// Problem: x [B=8, T=16, C=64, H=64, W=64] fp32.
// out = x masked by per-batch top-K (K=2048 of N=4096) spatial sites,
// score[b,n] = mean_t sqrt(sum_c x[b,t,c,n]^2).
//
// Scores are computed BIT-IDENTICALLY to numpy's reduction semantics
// (sequential ascending-index accumulation for non-innermost-axis reduce,
// unfused mul/add, IEEE sqrt, exact /16) so the top-K set matches the
// reference exactly -> absmax 0 at kept sites.

constexpr int NB = 8;
constexpr int NT = 16;
constexpr int NC = 64;
constexpr int NN = 4096;   // H*W
constexpr int KK = 2048;   // keep_k

// ---------------- Kernel A: sq[b,t,n] = sqrt(sum_c x[b,t,c,n]^2) ----------------
// One thread per 4 consecutive n (float4 loads, fully coalesced).
// c-loop accumulates sequentially c=0..63 (numpy order), unfused mul/add.
__global__ __launch_bounds__(256) void k_sq(const float* __restrict__ x,
                                            float* __restrict__ sq) {
    int idx = blockIdx.x * 256 + threadIdx.x;          // over NB*NT*(NN/4)
    if (idx >= NB * NT * (NN / 4)) return;
    int n4 = (idx & (NN / 4 - 1));                     // float4 index within N
    int bt = idx >> 10;                                // b*NT + t
    const float4* xp = (const float4*)(x + (size_t)bt * NC * NN) + n4;
    float a0 = 0.f, a1 = 0.f, a2 = 0.f, a3 = 0.f;
    #pragma unroll 8
    for (int c = 0; c < NC; ++c) {
        float4 v = xp[c * (NN / 4)];
        a0 = __fadd_rn(a0, __fmul_rn(v.x, v.x));
        a1 = __fadd_rn(a1, __fmul_rn(v.y, v.y));
        a2 = __fadd_rn(a2, __fmul_rn(v.z, v.z));
        a3 = __fadd_rn(a3, __fmul_rn(v.w, v.w));
    }
    float4 r;
    r.x = __fsqrt_rn(a0);
    r.y = __fsqrt_rn(a1);
    r.z = __fsqrt_rn(a2);
    r.w = __fsqrt_rn(a3);
    ((float4*)sq)[idx] = r;
}

// ---------------- Kernel B: score[b,n] = (sum_t sq[b,t,n]) * (1/16) ----------------
// t accumulated sequentially t=0..15 (numpy order).
__global__ __launch_bounds__(256) void k_score(const float* __restrict__ sq,
                                               float* __restrict__ scores) {
    int idx = blockIdx.x * 256 + threadIdx.x;          // over NB*(NN/4)
    if (idx >= NB * (NN / 4)) return;
    int b = idx >> 10;
    int n4 = idx & (NN / 4 - 1);
    const float4* sp = (const float4*)(sq + (size_t)b * NT * NN) + n4;
    float a0 = 0.f, a1 = 0.f, a2 = 0.f, a3 = 0.f;
    #pragma unroll
    for (int t = 0; t < NT; ++t) {
        float4 v = sp[t * (NN / 4)];
        a0 = __fadd_rn(a0, v.x);
        a1 = __fadd_rn(a1, v.y);
        a2 = __fadd_rn(a2, v.z);
        a3 = __fadd_rn(a3, v.w);
    }
    float4 r;
    r.x = __fmul_rn(a0, 0.0625f);
    r.y = __fmul_rn(a1, 0.0625f);
    r.z = __fmul_rn(a2, 0.0625f);
    r.w = __fmul_rn(a3, 0.0625f);
    ((float4*)scores)[idx] = r;
}

// ---------------- Fallback: fused score (if ws too small for sq) ----------------
__global__ __launch_bounds__(256) void k_score_fused(const float* __restrict__ x,
                                                     float* __restrict__ scores) {
    int idx = blockIdx.x * 256 + threadIdx.x;          // over NB*NN
    if (idx >= NB * NN) return;
    int b = idx >> 12;
    int n = idx & (NN - 1);
    const float* xb = x + (size_t)b * NT * NC * NN + n;
    float at = 0.f;
    for (int t = 0; t < NT; ++t) {
        float ac = 0.f;
        #pragma unroll 8
        for (int c = 0; c < NC; ++c) {
            float v = xb[(size_t)(t * NC + c) * NN];
            ac = __fadd_rn(ac, __fmul_rn(v, v));
        }
        at = __fadd_rn(at, __fsqrt_rn(ac));
    }
    scores[idx] = __fmul_rn(at, 0.0625f);
}

// ---------------- Kernel C: exact top-K membership mask ----------------
// rank(i) = #{j : s[j] > s[i]} + #{j < i : s[j] == s[i]}  (lax.top_k stable ties)
// keep iff rank < K. One block per 256 sites; whole batch's scores in LDS.
__global__ __launch_bounds__(256) void k_select(const float* __restrict__ scores,
                                                float* __restrict__ mask) {
    __shared__ float s[NN];                            // 16 KiB
    int b = blockIdx.x / (NN / 256);
    int seg = blockIdx.x % (NN / 256);
    const float* sb = scores + b * NN;
    for (int j = threadIdx.x; j < NN; j += 256) s[j] = sb[j];
    __syncthreads();
    int i = seg * 256 + threadIdx.x;
    float si = s[i];
    int cnt = 0;
    const float4* s4 = (const float4*)s;
    #pragma unroll 4
    for (int j4 = 0; j4 < NN / 4; ++j4) {
        float4 v = s4[j4];
        int j = j4 * 4;
        cnt += (v.x > si) || (v.x == si && (j + 0) < i);
        cnt += (v.y > si) || (v.y == si && (j + 1) < i);
        cnt += (v.z > si) || (v.z == si && (j + 2) < i);
        cnt += (v.w > si) || (v.w == si && (j + 3) < i);
    }
    mask[b * NN + i] = (cnt < KK) ? 1.0f : 0.0f;
}

// ---------------- Kernel D: out = mask ? x : 0 ----------------
__global__ __launch_bounds__(256) void k_apply(const float* __restrict__ x,
                                               const float* __restrict__ mask,
                                               float* __restrict__ out) {
    size_t i = (size_t)blockIdx.x * 256 + threadIdx.x; // over total/4 = 8,388,608
    int b = (int)(i >> 20);                            // NT*NC*NN/4 = 2^20 per batch
    int n4 = (int)(i & (NN / 4 - 1));
    float4 v = ((const float4*)x)[i];
    float4 m = ((const float4*)mask)[b * (NN / 4) + n4];
    float4 r;
    r.x = (m.x != 0.f) ? v.x : 0.f;
    r.y = (m.y != 0.f) ? v.y : 0.f;
    r.z = (m.z != 0.f) ? v.z : 0.f;
    r.w = (m.w != 0.f) ? v.w : 0.f;
    ((float4*)out)[i] = r;
}

extern "C" void kernel_launch(void* const* d_in, const int* in_sizes, int n_in,
                              void* d_out, int out_size, void* d_ws, size_t ws_size,
                              hipStream_t stream) {
    const float* x = (const float*)d_in[0];
    float* out = (float*)d_out;
    float* ws = (float*)d_ws;

    // ws layout (floats): scores [32768] | mask [32768] | sq [524288]
    float* scores = ws;
    float* mask   = ws + NB * NN;
    float* sq     = ws + 2 * NB * NN;
    const size_t need_fast = (size_t)(2 * NB * NN + NB * NT * NN) * sizeof(float);

    if (ws_size >= need_fast) {
        k_sq<<<(NB * NT * (NN / 4) + 255) / 256, 256, 0, stream>>>(x, sq);
        k_score<<<(NB * (NN / 4) + 255) / 256, 256, 0, stream>>>(sq, scores);
    } else {
        k_score_fused<<<(NB * NN + 255) / 256, 256, 0, stream>>>(x, scores);
    }
    k_select<<<NB * (NN / 256), 256, 0, stream>>>(scores, mask);
    k_apply<<<(NB * NT * NC * (NN / 4)) / 256, 256, 0, stream>>>(x, mask, out);
}

// Round 2
// 262.742 us; speedup vs baseline: 1.3148x; 1.3148x over previous
//
#include <hip/hip_runtime.h>

// Problem: x [B=8, T=16, C=64, H=64, W=64] fp32.
// out = x masked by per-batch top-K (K=2048 of N=4096) spatial sites,
// score[b,n] = mean_t sqrt(sum_c x[b,t,c,n]^2).
//
// Scores computed BIT-IDENTICALLY to numpy (sequential ascending-index
// accumulation, unfused mul/add, IEEE sqrt, *0.0625) -> kept set matches the
// reference exactly -> absmax 0 (verified R1).
//
// R2 change: O(N^2) rank-count select (103 us, 12% VALUBusy on 128 blocks)
// replaced with 32-step bit-bisection for the K-th largest score value
// (monotone bits for nonnegative floats) + exact prefix-scan tie handling.

constexpr int NB = 8;
constexpr int NT = 16;
constexpr int NC = 64;
constexpr int NN = 4096;   // H*W
constexpr int KK = 2048;   // keep_k

// ---------------- Kernel A: sq[b,t,n] = sqrt(sum_c x[b,t,c,n]^2) ----------------
__global__ __launch_bounds__(256) void k_sq(const float* __restrict__ x,
                                            float* __restrict__ sq) {
    int idx = blockIdx.x * 256 + threadIdx.x;          // over NB*NT*(NN/4)
    if (idx >= NB * NT * (NN / 4)) return;
    int n4 = (idx & (NN / 4 - 1));
    int bt = idx >> 10;
    const float4* xp = (const float4*)(x + (size_t)bt * NC * NN) + n4;
    float a0 = 0.f, a1 = 0.f, a2 = 0.f, a3 = 0.f;
    #pragma unroll 8
    for (int c = 0; c < NC; ++c) {
        float4 v = xp[c * (NN / 4)];
        a0 = __fadd_rn(a0, __fmul_rn(v.x, v.x));
        a1 = __fadd_rn(a1, __fmul_rn(v.y, v.y));
        a2 = __fadd_rn(a2, __fmul_rn(v.z, v.z));
        a3 = __fadd_rn(a3, __fmul_rn(v.w, v.w));
    }
    float4 r;
    r.x = __fsqrt_rn(a0);
    r.y = __fsqrt_rn(a1);
    r.z = __fsqrt_rn(a2);
    r.w = __fsqrt_rn(a3);
    ((float4*)sq)[idx] = r;
}

// ---------------- Fallback score (ws too small for sq): scores[b,n] ----------------
__global__ __launch_bounds__(256) void k_score_fused(const float* __restrict__ x,
                                                     float* __restrict__ scores) {
    int idx = blockIdx.x * 256 + threadIdx.x;
    if (idx >= NB * NN) return;
    int b = idx >> 12;
    int n = idx & (NN - 1);
    const float* xb = x + (size_t)b * NT * NC * NN + n;
    float at = 0.f;
    for (int t = 0; t < NT; ++t) {
        float ac = 0.f;
        #pragma unroll 8
        for (int c = 0; c < NC; ++c) {
            float v = xb[(size_t)(t * NC + c) * NN];
            ac = __fadd_rn(ac, __fmul_rn(v, v));
        }
        at = __fadd_rn(at, __fsqrt_rn(ac));
    }
    scores[idx] = __fmul_rn(at, 0.0625f);
}

// ---------------- Kernel B: top-K mask via bit-bisection ----------------
// One block per batch, 1024 threads; thread owns 4 consecutive sites.
// mode 0: src = sq  [NB][NT][NN] -> t-sum done here (sequential, *0.0625)
// mode 1: src = scores [NB][NN]
__global__ __launch_bounds__(1024) void k_select2(const float* __restrict__ src,
                                                  float* __restrict__ mask,
                                                  int mode) {
    __shared__ unsigned s_red[2][16];
    __shared__ unsigned s_scan[1024];

    int b = blockIdx.x;
    int tid = threadIdx.x;
    int wave = tid >> 6, lane = tid & 63;

    // --- scores for sites 4*tid .. 4*tid+3 (bit-identical to numpy) ---
    float sc0, sc1, sc2, sc3;
    if (mode == 0) {
        const float4* sp = (const float4*)(src + (size_t)b * NT * NN);
        float a0 = 0.f, a1 = 0.f, a2 = 0.f, a3 = 0.f;
        #pragma unroll
        for (int t = 0; t < NT; ++t) {
            float4 v = sp[t * (NN / 4) + tid];
            a0 = __fadd_rn(a0, v.x);
            a1 = __fadd_rn(a1, v.y);
            a2 = __fadd_rn(a2, v.z);
            a3 = __fadd_rn(a3, v.w);
        }
        sc0 = __fmul_rn(a0, 0.0625f);
        sc1 = __fmul_rn(a1, 0.0625f);
        sc2 = __fmul_rn(a2, 0.0625f);
        sc3 = __fmul_rn(a3, 0.0625f);
    } else {
        float4 v = ((const float4*)(src + (size_t)b * NN))[tid];
        sc0 = v.x; sc1 = v.y; sc2 = v.z; sc3 = v.w;
    }
    // nonnegative floats -> unsigned bit pattern is order-preserving
    unsigned u0 = __float_as_uint(sc0);
    unsigned u1 = __float_as_uint(sc1);
    unsigned u2 = __float_as_uint(sc2);
    unsigned u3 = __float_as_uint(sc3);

    // --- bisection: max T with count(u >= T) >= KK  ==> T = K-th largest value ---
    unsigned T = 0;
    for (int bit = 31; bit >= 0; --bit) {
        unsigned C = T | (1u << bit);
        int local = (int)(u0 >= C) + (int)(u1 >= C) + (int)(u2 >= C) + (int)(u3 >= C);
        #pragma unroll
        for (int off = 32; off > 0; off >>= 1)
            local += __shfl_down(local, off, 64);
        if (lane == 0) s_red[bit & 1][wave] = (unsigned)local;
        __syncthreads();
        int total = 0;
        #pragma unroll
        for (int w = 0; w < 16; ++w) total += (int)s_red[bit & 1][w];
        if (total >= KK) T = C;
        // no second sync: next iter writes the other slot; the slot reused two
        // iters later is separated by an intervening __syncthreads
    }

    // --- cnt_gt = count(u > T) ---
    {
        int local = (int)(u0 > T) + (int)(u1 > T) + (int)(u2 > T) + (int)(u3 > T);
        #pragma unroll
        for (int off = 32; off > 0; off >>= 1)
            local += __shfl_down(local, off, 64);
        if (lane == 0) s_red[0][wave] = (unsigned)local;
    }
    __syncthreads();
    int cnt_gt = 0;
    #pragma unroll
    for (int w = 0; w < 16; ++w) cnt_gt += (int)s_red[0][w];
    int keep_eq = KK - cnt_gt;   // #ties to keep, ascending index (stable top_k)

    // --- exact exclusive prefix over equality flags (ascending site index) ---
    int e0 = (u0 == T), e1 = (u1 == T), e2 = (u2 == T), e3 = (u3 == T);
    int lsum = e0 + e1 + e2 + e3;
    s_scan[tid] = (unsigned)lsum;
    __syncthreads();
    for (int off = 1; off < 1024; off <<= 1) {
        unsigned v = (tid >= off) ? s_scan[tid - off] : 0u;
        __syncthreads();
        s_scan[tid] += v;
        __syncthreads();
    }
    int excl = (int)s_scan[tid] - lsum;  // equals before this thread's chunk

    float4 m;
    m.x = ((u0 > T) || (e0 && (excl) < keep_eq)) ? 1.f : 0.f;
    m.y = ((u1 > T) || (e1 && (excl + e0) < keep_eq)) ? 1.f : 0.f;
    m.z = ((u2 > T) || (e2 && (excl + e0 + e1) < keep_eq)) ? 1.f : 0.f;
    m.w = ((u3 > T) || (e3 && (excl + e0 + e1 + e2) < keep_eq)) ? 1.f : 0.f;
    ((float4*)(mask + (size_t)b * NN))[tid] = m;
}

// ---------------- Kernel C: out = mask ? x : 0 ----------------
__global__ __launch_bounds__(256) void k_apply(const float* __restrict__ x,
                                               const float* __restrict__ mask,
                                               float* __restrict__ out) {
    size_t i = (size_t)blockIdx.x * 256 + threadIdx.x; // over total/4
    int b = (int)(i >> 20);                            // NT*NC*NN/4 = 2^20 per batch
    int n4 = (int)(i & (NN / 4 - 1));
    float4 v = ((const float4*)x)[i];
    float4 m = ((const float4*)mask)[b * (NN / 4) + n4];
    float4 r;
    r.x = (m.x != 0.f) ? v.x : 0.f;
    r.y = (m.y != 0.f) ? v.y : 0.f;
    r.z = (m.z != 0.f) ? v.z : 0.f;
    r.w = (m.w != 0.f) ? v.w : 0.f;
    ((float4*)out)[i] = r;
}

extern "C" void kernel_launch(void* const* d_in, const int* in_sizes, int n_in,
                              void* d_out, int out_size, void* d_ws, size_t ws_size,
                              hipStream_t stream) {
    const float* x = (const float*)d_in[0];
    float* out = (float*)d_out;
    float* ws = (float*)d_ws;

    // ws layout (floats): mask [NB*NN] | sq [NB*NT*NN]   (fallback: scores in sq slot)
    float* mask = ws;
    float* sq   = ws + NB * NN;
    const size_t need_fast = (size_t)(NB * NN + NB * NT * NN) * sizeof(float);

    if (ws_size >= need_fast) {
        k_sq<<<(NB * NT * (NN / 4) + 255) / 256, 256, 0, stream>>>(x, sq);
        k_select2<<<NB, 1024, 0, stream>>>(sq, mask, 0);
    } else {
        k_score_fused<<<(NB * NN + 255) / 256, 256, 0, stream>>>(x, sq);
        k_select2<<<NB, 1024, 0, stream>>>(sq, mask, 1);
    }
    k_apply<<<(NB * NT * NC * (NN / 4)) / 256, 256, 0, stream>>>(x, mask, out);
}

// Round 4
// 257.240 us; speedup vs baseline: 1.3429x; 1.0214x over previous
//
#include <hip/hip_runtime.h>

// Problem: x [B=8, T=16, C=64, H=64, W=64] fp32.
// out = x masked by per-batch top-K (K=2048 of N=4096) spatial sites,
// score[b,n] = mean_t sqrt(sum_c x[b,t,c,n]^2).
//
// Scores computed BIT-IDENTICALLY to numpy (sequential ascending-index
// accumulation, unfused mul/add, IEEE sqrt, *0.0625) -> kept set matches the
// reference exactly -> absmax 0 (verified R1, R2).
//
// R4: fix nontemporal builtin types (clang ext_vector_type, not
// HIP_vector_type). Otherwise same as R3: k_score split out (32 blocks),
// k_select3 (256 thr/block, common-prefix bisection skip), nontemporal
// k_apply, unroll 16 k_sq.

constexpr int NB = 8;
constexpr int NT = 16;
constexpr int NC = 64;
constexpr int NN = 4096;   // H*W
constexpr int KK = 2048;   // keep_k

typedef float vf4 __attribute__((ext_vector_type(4)));  // raw vec for nt builtins

// ---------------- Kernel A: sq[b,t,n] = sqrt(sum_c x[b,t,c,n]^2) ----------------
__global__ __launch_bounds__(256) void k_sq(const float* __restrict__ x,
                                            float* __restrict__ sq) {
    int idx = blockIdx.x * 256 + threadIdx.x;          // over NB*NT*(NN/4)
    if (idx >= NB * NT * (NN / 4)) return;
    int n4 = (idx & (NN / 4 - 1));
    int bt = idx >> 10;
    const float4* xp = (const float4*)(x + (size_t)bt * NC * NN) + n4;
    float a0 = 0.f, a1 = 0.f, a2 = 0.f, a3 = 0.f;
    #pragma unroll 16
    for (int c = 0; c < NC; ++c) {
        float4 v = xp[c * (NN / 4)];
        a0 = __fadd_rn(a0, __fmul_rn(v.x, v.x));
        a1 = __fadd_rn(a1, __fmul_rn(v.y, v.y));
        a2 = __fadd_rn(a2, __fmul_rn(v.z, v.z));
        a3 = __fadd_rn(a3, __fmul_rn(v.w, v.w));
    }
    float4 r;
    r.x = __fsqrt_rn(a0);
    r.y = __fsqrt_rn(a1);
    r.z = __fsqrt_rn(a2);
    r.w = __fsqrt_rn(a3);
    ((float4*)sq)[idx] = r;
}

// ---------------- Kernel B: score[b,n] = (sum_t sq[b,t,n]) * (1/16) ----------------
__global__ __launch_bounds__(256) void k_score(const float* __restrict__ sq,
                                               float* __restrict__ scores) {
    int idx = blockIdx.x * 256 + threadIdx.x;          // over NB*(NN/4) -> 32 blocks
    if (idx >= NB * (NN / 4)) return;
    int b = idx >> 10;
    int n4 = idx & (NN / 4 - 1);
    const float4* sp = (const float4*)(sq + (size_t)b * NT * NN) + n4;
    float a0 = 0.f, a1 = 0.f, a2 = 0.f, a3 = 0.f;
    #pragma unroll
    for (int t = 0; t < NT; ++t) {
        float4 v = sp[t * (NN / 4)];
        a0 = __fadd_rn(a0, v.x);
        a1 = __fadd_rn(a1, v.y);
        a2 = __fadd_rn(a2, v.z);
        a3 = __fadd_rn(a3, v.w);
    }
    float4 r;
    r.x = __fmul_rn(a0, 0.0625f);
    r.y = __fmul_rn(a1, 0.0625f);
    r.z = __fmul_rn(a2, 0.0625f);
    r.w = __fmul_rn(a3, 0.0625f);
    ((float4*)scores)[idx] = r;
}

// ---------------- Fallback score (ws too small for sq) ----------------
__global__ __launch_bounds__(256) void k_score_fused(const float* __restrict__ x,
                                                     float* __restrict__ scores) {
    int idx = blockIdx.x * 256 + threadIdx.x;
    if (idx >= NB * NN) return;
    int b = idx >> 12;
    int n = idx & (NN - 1);
    const float* xb = x + (size_t)b * NT * NC * NN + n;
    float at = 0.f;
    for (int t = 0; t < NT; ++t) {
        float ac = 0.f;
        #pragma unroll 8
        for (int c = 0; c < NC; ++c) {
            float v = xb[(size_t)(t * NC + c) * NN];
            ac = __fadd_rn(ac, __fmul_rn(v, v));
        }
        at = __fadd_rn(at, __fsqrt_rn(ac));
    }
    scores[idx] = __fmul_rn(at, 0.0625f);
}

// ---------------- Kernel C: top-K mask, bit-bisection w/ prefix skip ----------------
// One block (256 threads = 4 waves) per batch; thread owns 16 consecutive sites.
__global__ __launch_bounds__(256) void k_select3(const float* __restrict__ scores,
                                                 float* __restrict__ mask) {
    __shared__ unsigned s_red[2][4];
    __shared__ unsigned s_scan[4];

    int b = blockIdx.x;
    int tid = threadIdx.x;
    int wave = tid >> 6, lane = tid & 63;

    // load 16 scores (sites tid*16 .. tid*16+15); nonneg -> bits order-preserving
    unsigned u[16];
    const float4* sp = (const float4*)(scores + (size_t)b * NN);
    #pragma unroll
    for (int k = 0; k < 4; ++k) {
        float4 v = sp[tid * 4 + k];
        u[4 * k + 0] = __float_as_uint(v.x);
        u[4 * k + 1] = __float_as_uint(v.y);
        u[4 * k + 2] = __float_as_uint(v.z);
        u[4 * k + 3] = __float_as_uint(v.w);
    }

    // --- block min/max of u -> common high-bit prefix ---
    unsigned lmin = u[0], lmax = u[0];
    #pragma unroll
    for (int k = 1; k < 16; ++k) {
        lmin = min(lmin, u[k]);
        lmax = max(lmax, u[k]);
    }
    #pragma unroll
    for (int off = 32; off > 0; off >>= 1) {
        lmin = min(lmin, (unsigned)__shfl_down((int)lmin, off, 64));
        lmax = max(lmax, (unsigned)__shfl_down((int)lmax, off, 64));
    }
    if (lane == 0) { s_red[0][wave] = lmin; s_red[1][wave] = lmax; }
    __syncthreads();
    unsigned umin = s_red[0][0], umax = s_red[1][0];
    #pragma unroll
    for (int w = 1; w < 4; ++w) {
        umin = min(umin, s_red[0][w]);
        umax = max(umax, s_red[1][w]);
    }
    __syncthreads();

    // --- bisection: max T with count(u >= T) >= KK (T = K-th largest bits) ---
    unsigned T;
    if (umax == umin) {
        T = umax;                      // all equal: pure tie case
    } else {
        int hb = 31 - __clz(umax ^ umin);      // hb <= 30 (scores >= 0)
        T = umax & ~((2u << hb) - 1);          // shared prefix, low bits 0
        for (int bit = hb; bit >= 0; --bit) {
            unsigned C = T | (1u << bit);
            int local = 0;
            #pragma unroll
            for (int k = 0; k < 16; ++k) local += (int)(u[k] >= C);
            #pragma unroll
            for (int off = 32; off > 0; off >>= 1)
                local += __shfl_down(local, off, 64);
            if (lane == 0) s_red[bit & 1][wave] = (unsigned)local;
            __syncthreads();
            int total = (int)s_red[bit & 1][0] + (int)s_red[bit & 1][1] +
                        (int)s_red[bit & 1][2] + (int)s_red[bit & 1][3];
            if (total >= KK) T = C;
            // alternating slot: entry reused two iters later, separated by a sync
        }
    }

    // --- cnt_gt = count(u > T) ---
    {
        int local = 0;
        #pragma unroll
        for (int k = 0; k < 16; ++k) local += (int)(u[k] > T);
        #pragma unroll
        for (int off = 32; off > 0; off >>= 1)
            local += __shfl_down(local, off, 64);
        __syncthreads();
        if (lane == 0) s_red[0][wave] = (unsigned)local;
    }
    __syncthreads();
    int cnt_gt = (int)s_red[0][0] + (int)s_red[0][1] +
                 (int)s_red[0][2] + (int)s_red[0][3];
    int keep_eq = KK - cnt_gt;         // #ties kept, ascending index (stable top_k)

    // --- exclusive prefix of equality counts across threads (ascending n) ---
    int lsum = 0;
    #pragma unroll
    for (int k = 0; k < 16; ++k) lsum += (int)(u[k] == T);
    int incl = lsum;
    #pragma unroll
    for (int off = 1; off < 64; off <<= 1) {
        int v = __shfl_up(incl, off, 64);
        if (lane >= off) incl += v;
    }
    if (lane == 63) s_scan[wave] = (unsigned)incl;
    __syncthreads();
    int woff = 0;
    for (int w = 0; w < wave; ++w) woff += (int)s_scan[w];
    int run = woff + incl - lsum;      // equal-count before this thread's chunk

    // --- emit mask ---
    #pragma unroll
    for (int k = 0; k < 4; ++k) {
        float4 m;
        float* mp = (float*)&m;
        #pragma unroll
        for (int j = 0; j < 4; ++j) {
            unsigned uv = u[4 * k + j];
            int e = (uv == T);
            mp[j] = ((uv > T) || (e && run < keep_eq)) ? 1.f : 0.f;
            run += e;
        }
        ((float4*)(mask + (size_t)b * NN))[tid * 4 + k] = m;
    }
}

// ---------------- Kernel D: out = mask ? x : 0 ----------------
__global__ __launch_bounds__(256) void k_apply(const float* __restrict__ x,
                                               const float* __restrict__ mask,
                                               float* __restrict__ out) {
    size_t i = (size_t)blockIdx.x * 256 + threadIdx.x; // over total/4
    int b = (int)(i >> 20);                            // NT*NC*NN/4 = 2^20 per batch
    int n4 = (int)(i & (NN / 4 - 1));
    vf4 v = __builtin_nontemporal_load((const vf4*)x + i);
    float4 m = ((const float4*)mask)[b * (NN / 4) + n4];
    vf4 r;
    r.x = (m.x != 0.f) ? v.x : 0.f;
    r.y = (m.y != 0.f) ? v.y : 0.f;
    r.z = (m.z != 0.f) ? v.z : 0.f;
    r.w = (m.w != 0.f) ? v.w : 0.f;
    __builtin_nontemporal_store(r, (vf4*)out + i);
}

extern "C" void kernel_launch(void* const* d_in, const int* in_sizes, int n_in,
                              void* d_out, int out_size, void* d_ws, size_t ws_size,
                              hipStream_t stream) {
    const float* x = (const float*)d_in[0];
    float* out = (float*)d_out;
    float* ws = (float*)d_ws;

    // ws layout (floats): mask [NB*NN] | scores [NB*NN] | sq [NB*NT*NN]
    float* mask   = ws;
    float* scores = ws + NB * NN;
    float* sq     = ws + 2 * NB * NN;
    const size_t need_fast = (size_t)(2 * NB * NN + NB * NT * NN) * sizeof(float);

    if (ws_size >= need_fast) {
        k_sq<<<(NB * NT * (NN / 4) + 255) / 256, 256, 0, stream>>>(x, sq);
        k_score<<<(NB * (NN / 4) + 255) / 256, 256, 0, stream>>>(sq, scores);
    } else {
        k_score_fused<<<(NB * NN + 255) / 256, 256, 0, stream>>>(x, scores);
    }
    k_select3<<<NB, 256, 0, stream>>>(scores, mask);
    k_apply<<<(NB * NT * NC * (NN / 4)) / 256, 256, 0, stream>>>(x, mask, out);
}